// Round 1
// baseline (6143.789 us; speedup 1.0000x reference)
//
#include <hip/hip_runtime.h>
#include <math.h>

#define BB 32
#define NN 2048
#define D_IN 320
#define H1 160
#define H2 80
#define H3 40
#define H4 5

// ---------------------------------------------------------------------------
// MLP: h2 = relu(relu(x@W1+b1)@W2+b2), 2 rows per block, 320 threads.
// Also writes transposed layout h2T[b][c][n] and row norms sq2[b][n].
// ---------------------------------------------------------------------------
__global__ __launch_bounds__(320) void mlp_kernel(
    const float* __restrict__ x,  const float* __restrict__ W1, const float* __restrict__ b1,
    const float* __restrict__ W2, const float* __restrict__ b2,
    float* __restrict__ h2, float* __restrict__ h2T, float* __restrict__ sq2)
{
    __shared__ float xs[2][D_IN];
    __shared__ float h1s[2][H1];
    __shared__ float o2[2][H2];

    const int t = threadIdx.x;
    const int row0 = blockIdx.x * 2;

    xs[0][t] = x[row0 * D_IN + t];
    xs[1][t] = x[(row0 + 1) * D_IN + t];
    __syncthreads();

    // layer 1: 320 threads = (r in 0..1) x (j in 0..159)
    {
        const int j = t % H1, r = t / H1;
        float acc = b1[j];
        #pragma unroll 4
        for (int c = 0; c < D_IN; ++c) acc += xs[r][c] * W1[c * H1 + j];
        h1s[r][j] = fmaxf(acc, 0.f);
    }
    __syncthreads();

    // layer 2: threads 0..159 = (r in 0..1) x (k in 0..79)
    if (t < 2 * H2) {
        const int k = t % H2, r = t / H2;
        float acc = b2[k];
        #pragma unroll 4
        for (int j = 0; j < H1; ++j) acc += h1s[r][j] * W2[j * H2 + k];
        acc = fmaxf(acc, 0.f);
        o2[r][k] = acc;
        const int row = row0 + r;
        const int b = row / NN, n = row % NN;
        h2[row * H2 + k] = acc;
        h2T[(b * H2 + k) * NN + n] = acc;
    }
    __syncthreads();

    if (t < 2) {
        float s = 0.f;
        for (int k = 0; k < H2; ++k) s += o2[t][k] * o2[t][k];
        sq2[row0 + t] = s;
    }
}

// ---------------------------------------------------------------------------
// Graph conv: A = softmax_m(2*h_n.h_m - |h_m|^2); out = relu((A@h)@W + b).
// R=4 rows per block, 256 threads (4 waves; wave w owns row w for softmax).
// ---------------------------------------------------------------------------
template<int C_IN, int C_OUT, bool DO_MEAN>
__global__ __launch_bounds__(256) void conv_kernel(
    const float* __restrict__ h,  const float* __restrict__ hT, const float* __restrict__ sq,
    const float* __restrict__ W,  const float* __restrict__ bias,
    float* __restrict__ ho, float* __restrict__ hoT, float* __restrict__ sqo,
    float* __restrict__ mean_out)
{
    constexpr int R = 4;
    constexpr int G = 256 / C_IN;           // 3 for C_IN=80, 6 for C_IN=40
    __shared__ float hn[R][C_IN];
    __shared__ float sc[R][NN];             // scores -> unnormalized probs
    __shared__ float part[G][R][C_IN];
    __shared__ float agg[R][C_IN];
    __shared__ float denom[R];
    __shared__ float outv[R][C_OUT];

    const int t  = threadIdx.x;
    const int b  = blockIdx.x / (NN / R);
    const int n0 = (blockIdx.x % (NN / R)) * R;

    for (int i = t; i < R * C_IN; i += 256) {
        const int r = i / C_IN, c = i % C_IN;
        hn[r][c] = h[(b * NN + n0 + r) * C_IN + c];
    }
    __syncthreads();

    const float* hTb = hT + b * C_IN * NN;
    const float* sqb = sq + b * NN;

    // score phase: coalesced reads of hT[c][m], 4 rows reuse each load
    for (int m = t; m < NN; m += 256) {
        float d0 = 0.f, d1 = 0.f, d2 = 0.f, d3 = 0.f;
        #pragma unroll 4
        for (int c = 0; c < C_IN; ++c) {
            const float v = hTb[c * NN + m];
            d0 += hn[0][c] * v; d1 += hn[1][c] * v;
            d2 += hn[2][c] * v; d3 += hn[3][c] * v;
        }
        const float q = sqb[m];
        sc[0][m] = 2.f * d0 - q;
        sc[1][m] = 2.f * d1 - q;
        sc[2][m] = 2.f * d2 - q;
        sc[3][m] = 2.f * d3 - q;
    }
    __syncthreads();

    // softmax: wave w handles row w
    {
        const int w = t >> 6, lane = t & 63;
        float mx = -INFINITY;
        for (int m = lane; m < NN; m += 64) mx = fmaxf(mx, sc[w][m]);
        #pragma unroll
        for (int off = 32; off; off >>= 1) mx = fmaxf(mx, __shfl_xor(mx, off));
        float sum = 0.f;
        for (int m = lane; m < NN; m += 64) {
            const float e = __expf(sc[w][m] - mx);
            sc[w][m] = e;
            sum += e;
        }
        #pragma unroll
        for (int off = 32; off; off >>= 1) sum += __shfl_xor(sum, off);
        if (lane == 0) denom[w] = sum;
    }
    __syncthreads();

    // aggregation: thread (c,g) accumulates over m = g, g+G, ... (coalesced in c)
    if (t < G * C_IN) {
        const int c = t % C_IN, g = t / C_IN;
        float a0 = 0.f, a1 = 0.f, a2 = 0.f, a3 = 0.f;
        const float* hb = h + b * NN * C_IN;
        for (int m = g; m < NN; m += G) {
            const float v = hb[m * C_IN + c];
            a0 += sc[0][m] * v; a1 += sc[1][m] * v;
            a2 += sc[2][m] * v; a3 += sc[3][m] * v;
        }
        part[g][0][c] = a0; part[g][1][c] = a1;
        part[g][2][c] = a2; part[g][3][c] = a3;
    }
    __syncthreads();

    for (int i = t; i < R * C_IN; i += 256) {
        const int r = i / C_IN, c = i % C_IN;
        float s = 0.f;
        #pragma unroll
        for (int g = 0; g < G; ++g) s += part[g][r][c];
        agg[r][c] = s / denom[r];
    }
    __syncthreads();

    // output projection + relu (+ optional transposed store / norms / mean)
    if (t < R * C_OUT) {
        const int j = t % C_OUT, r = t / C_OUT;
        float acc = bias[j];
        #pragma unroll
        for (int c = 0; c < C_IN; ++c) acc += agg[r][c] * W[c * C_OUT + j];
        acc = fmaxf(acc, 0.f);
        outv[r][j] = acc;
        const int n = n0 + r;
        if (ho)  ho [(b * NN + n) * C_OUT + j] = acc;
        if (hoT) hoT[(b * C_OUT + j) * NN + n] = acc;
        if (DO_MEAN) atomicAdd(&mean_out[b * C_OUT + j], acc * (1.f / NN));
    }
    __syncthreads();

    if (sqo != nullptr && t < R) {
        float s = 0.f;
        for (int j = 0; j < C_OUT; ++j) s += outv[t][j] * outv[t][j];
        sqo[b * NN + n0 + t] = s;
    }
}

// ---------------------------------------------------------------------------
// Final classifier + softmax over 2 logits. 64 threads = 32 batches x 2.
// ---------------------------------------------------------------------------
__global__ __launch_bounds__(64) void final_kernel(
    const float* __restrict__ mean, const float* __restrict__ Wf,
    const float* __restrict__ bf, float* __restrict__ out)
{
    const int t = threadIdx.x;
    const int b = t >> 1, k = t & 1;
    float acc = bf[k];
    #pragma unroll
    for (int c = 0; c < H4; ++c) acc += mean[b * H4 + c] * Wf[c * 2 + k];
    const float other = __shfl_xor(acc, 1);
    const float mx = fmaxf(acc, other);
    const float e  = __expf(acc - mx);
    const float eo = __expf(other - mx);
    out[t] = e / (e + eo);
}

extern "C" void kernel_launch(void* const* d_in, const int* in_sizes, int n_in,
                              void* d_out, int out_size, void* d_ws, size_t ws_size,
                              hipStream_t stream) {
    const float* x   = (const float*)d_in[0];
    const float* W1  = (const float*)d_in[1];
    const float* b1  = (const float*)d_in[2];
    const float* W2  = (const float*)d_in[3];
    const float* b2  = (const float*)d_in[4];
    const float* Wg1 = (const float*)d_in[5];
    const float* bg1 = (const float*)d_in[6];
    const float* Wg2 = (const float*)d_in[7];
    const float* bg2 = (const float*)d_in[8];
    const float* Wf  = (const float*)d_in[9];
    const float* bf  = (const float*)d_in[10];

    float* ws   = (float*)d_ws;
    float* h2   = ws;                        // B*N*80
    float* h2T  = h2  + BB * NN * H2;        // B*80*N
    float* sq2  = h2T + BB * NN * H2;        // B*N
    float* h3   = sq2 + BB * NN;             // B*N*40
    float* h3T  = h3  + BB * NN * H3;        // B*40*N
    float* sq3  = h3T + BB * NN * H3;        // B*N
    float* mean = sq3 + BB * NN;             // B*5

    hipMemsetAsync(mean, 0, BB * H4 * sizeof(float), stream);

    mlp_kernel<<<BB * NN / 2, 320, 0, stream>>>(x, W1, b1, W2, b2, h2, h2T, sq2);
    conv_kernel<H2, H3, false><<<BB * NN / 4, 256, 0, stream>>>(
        h2, h2T, sq2, Wg1, bg1, h3, h3T, sq3, nullptr);
    conv_kernel<H3, H4, true><<<BB * NN / 4, 256, 0, stream>>>(
        h3, h3T, sq3, Wg2, bg2, nullptr, nullptr, nullptr, mean);
    final_kernel<<<1, 64, 0, stream>>>(mean, Wf, bf, (float*)d_out);
}

// Round 2
// 730.038 us; speedup vs baseline: 8.4157x; 8.4157x over previous
//
#include <hip/hip_runtime.h>
#include <math.h>

#define BB 32
#define NN 2048
#define D_IN 320
#define H1 160
#define H2 80
#define H4 5

typedef __attribute__((ext_vector_type(8))) short short8;
typedef __attribute__((ext_vector_type(4))) float f32x4;

__device__ inline ushort f2bf(float f) {
    union { float f; unsigned u; } v; v.f = f;
    unsigned r = v.u + 0x7fff + ((v.u >> 16) & 1);   // RNE; inputs never NaN here
    return (ushort)(r >> 16);
}
__device__ inline float bf2f(ushort u) {
    union { float f; unsigned u; } v; v.u = ((unsigned)u) << 16;
    return v.f;
}

// ---------------------------------------------------------------------------
// MLP: h2 = relu(relu(x@W1+b1)@W2+b2). 8 rows/block, 320 threads.
// Emits bf16 h2 padded to 96 ch, bf16 h2T [b][96][N], and sq2 = |bf16(h2)|^2.
// ---------------------------------------------------------------------------
__global__ __launch_bounds__(320) void mlp_kernel(
    const float* __restrict__ x,  const float* __restrict__ W1, const float* __restrict__ b1,
    const float* __restrict__ W2, const float* __restrict__ b2,
    ushort* __restrict__ h2, ushort* __restrict__ h2T, float* __restrict__ sq2)
{
    __shared__ float xs[8][D_IN];
    __shared__ float h1s[8][H1];
    __shared__ float o2[8][H2];

    const int t = threadIdx.x;
    const int row0 = blockIdx.x * 8;

    #pragma unroll
    for (int i = 0; i < 8; ++i) xs[i][t] = x[(size_t)(row0 + i) * D_IN + t];
    __syncthreads();

    { // layer 1: 320 threads = (half 0..1) x (j 0..159), 4 rows each
        const int j = t % H1, half = t / H1;
        float a0 = b1[j], a1 = a0, a2 = a0, a3 = a0;
        for (int c = 0; c < D_IN; ++c) {
            const float wv = W1[c * H1 + j];
            a0 = fmaf(xs[half*4+0][c], wv, a0);
            a1 = fmaf(xs[half*4+1][c], wv, a1);
            a2 = fmaf(xs[half*4+2][c], wv, a2);
            a3 = fmaf(xs[half*4+3][c], wv, a3);
        }
        h1s[half*4+0][j] = fmaxf(a0, 0.f);
        h1s[half*4+1][j] = fmaxf(a1, 0.f);
        h1s[half*4+2][j] = fmaxf(a2, 0.f);
        h1s[half*4+3][j] = fmaxf(a3, 0.f);
    }
    __syncthreads();

    const int b = row0 / NN, n = row0 % NN;
    { // layer 2: (g 0..3) x (k 0..79), rows g and g+4
        const int k = t % H2, g = t / H2;
        float c0 = b2[k], c1 = b2[k];
        for (int j = 0; j < H1; ++j) {
            const float wv = W2[j * H2 + k];
            c0 = fmaf(h1s[g][j],     wv, c0);
            c1 = fmaf(h1s[g + 4][j], wv, c1);
        }
        const ushort u0 = f2bf(fmaxf(c0, 0.f));
        const ushort u1 = f2bf(fmaxf(c1, 0.f));
        o2[g][k]     = bf2f(u0);            // rounded values -> consistent sq
        o2[g + 4][k] = bf2f(u1);
        h2[(size_t)(row0 + g)     * 96 + k] = u0;
        h2[(size_t)(row0 + g + 4) * 96 + k] = u1;
        h2T[((size_t)b * 96 + k) * NN + n + g]     = u0;
        h2T[((size_t)b * 96 + k) * NN + n + g + 4] = u1;
    }
    // zero channel pads (80..95) in both layouts
    if (t < 128) {
        const int r = t >> 4, c = 80 + (t & 15);
        h2[(size_t)(row0 + r) * 96 + c] = 0;
    }
    if (t < 128) {
        const int c = 80 + (t >> 3), nn2 = t & 7;
        h2T[((size_t)b * 96 + c) * NN + n + nn2] = 0;
    }
    __syncthreads();
    if (t < 8) {
        float s = 0.f;
        for (int k = 0; k < H2; ++k) s += o2[t][k] * o2[t][k];
        sq2[row0 + t] = s;
    }
}

// ---------------------------------------------------------------------------
// Flash-attention graph conv on bf16 MFMA 16x16x32.
//   scores = 2*h_n.h_m - |h_m|^2 ; P = softmax_m ; out = relu((P@h)@W + b)
// Block: 256 thr / 4 waves; 64 Q-rows per block (16 per wave); keys in 64-chunks.
// ---------------------------------------------------------------------------
template<int C_PAD, int C_IN_REAL, int C_OUT, int JS, bool HAS_OUT, bool DO_MEAN>
__global__ __launch_bounds__(256) void attn_conv_kernel(
    const ushort* __restrict__ h, const ushort* __restrict__ hT,
    const float* __restrict__ sqg,
    const float* __restrict__ W, const float* __restrict__ bias,
    ushort* __restrict__ ho, ushort* __restrict__ hoT, float* __restrict__ sqo,
    float* __restrict__ mean_out)
{
    constexpr int KF  = C_PAD / 32;      // k-frags per 32-chunk (3 or 2)
    constexpr int CS  = C_PAD / 16;      // O column subtiles (6 or 4)
    constexpr int KST = C_PAD + 8;       // Krow LDS stride (bf16) — +8 kills bank conflicts
    constexpr int VST = 64 + 8;          // Vcol LDS stride
    constexpr int POS = C_PAD + 8;       // P/O transpose buffer stride

    __shared__ __attribute__((aligned(16))) ushort Krow[64 * KST];
    __shared__ __attribute__((aligned(16))) ushort Vcol[C_PAD * VST];
    __shared__ __attribute__((aligned(16))) ushort PObuf[4 * 16 * POS];
    __shared__ __attribute__((aligned(16))) ushort Wt[JS * 16 * POS];
    __shared__ float biasS[JS * 16];
    __shared__ float sqs[64];

    const int t = threadIdx.x;
    const int lane = t & 63, w = t >> 6;
    const int colid = lane & 15, quad = lane >> 4;
    const int b = blockIdx.x >> 5;             // NN/64 = 32 row-tiles per batch
    const int n0blk = (blockIdx.x & 31) * 64;

    // stage W^T (bf16, zero-padded) + bias, resident for the whole block
    for (int id = t; id < JS * 16 * C_PAD; id += 256) {
        const int j = id / C_PAD, c = id % C_PAD;
        const float v = (j < C_OUT && c < C_IN_REAL) ? W[c * C_OUT + j] : 0.f;
        Wt[j * POS + c] = f2bf(v);
    }
    if (t < JS * 16) biasS[t] = (t < C_OUT) ? bias[t] : 0.f;

    // Q A-frags: lane holds Q[m=lane&15][k=quad*8+j]  (m120-verified layout)
    short8 qf[KF];
    {
        const ushort* qrow = h + (size_t)((size_t)b * NN + n0blk + w * 16 + colid) * C_PAD;
        #pragma unroll
        for (int kf = 0; kf < KF; ++kf)
            qf[kf] = *(const short8*)&qrow[kf * 32 + quad * 8];
    }

    f32x4 o[CS];
    #pragma unroll
    for (int cs = 0; cs < CS; ++cs) o[cs] = (f32x4){0.f, 0.f, 0.f, 0.f};
    float mrun[4] = {-INFINITY, -INFINITY, -INFINITY, -INFINITY};
    float lrun[4] = {0.f, 0.f, 0.f, 0.f};

    ushort* PO = PObuf + w * 16 * POS;
    const float LOG2E = 1.44269504088896340736f;

    for (int n0 = 0; n0 < NN; n0 += 64) {
        // ---- stage K tile (row-major) and V tile (transposed) + sq ----
        const ushort* hsrc = h + (size_t)((size_t)b * NN + n0) * C_PAD;
        for (int id = t; id < 64 * C_PAD / 8; id += 256) {
            const int row = id / (C_PAD / 8), part = id % (C_PAD / 8);
            *(short8*)&Krow[row * KST + part * 8] = *(const short8*)&hsrc[id * 8];
        }
        for (int id = t; id < C_PAD * 8; id += 256) {
            const int c = id >> 3, part = id & 7;
            *(short8*)&Vcol[c * VST + part * 8] =
                *(const short8*)&hT[((size_t)b * C_PAD + c) * NN + n0 + part * 8];
        }
        if (t < 64) sqs[t] = sqg[b * NN + n0 + t];
        __syncthreads();

        // ---- S tiles: 4 col-subtiles of 16, scores scaled by log2(e) ----
        f32x4 s[4];
        #pragma unroll
        for (int ns = 0; ns < 4; ++ns) {
            f32x4 acc = (f32x4){0.f, 0.f, 0.f, 0.f};
            #pragma unroll
            for (int kf = 0; kf < KF; ++kf) {
                const short8 bf = *(const short8*)&Krow[(ns * 16 + colid) * KST + kf * 32 + quad * 8];
                acc = __builtin_amdgcn_mfma_f32_16x16x32_bf16(qf[kf], bf, acc, 0, 0, 0);
            }
            const float sqv = sqs[ns * 16 + colid];
            #pragma unroll
            for (int r = 0; r < 4; ++r)
                acc[r] = (2.f * acc[r] - sqv) * LOG2E;
            s[ns] = acc;
        }

        // ---- online softmax (rows = quad*4+r, reduce across 16 lanes) ----
        float mx[4];
        #pragma unroll
        for (int r = 0; r < 4; ++r)
            mx[r] = fmaxf(fmaxf(s[0][r], s[1][r]), fmaxf(s[2][r], s[3][r]));
        #pragma unroll
        for (int m = 1; m <= 8; m <<= 1)
            #pragma unroll
            for (int r = 0; r < 4; ++r) mx[r] = fmaxf(mx[r], __shfl_xor(mx[r], m));

        float alpha[4], rs[4];
        #pragma unroll
        for (int r = 0; r < 4; ++r) {
            const float mn = fmaxf(mrun[r], mx[r]);
            alpha[r] = exp2f(mrun[r] - mn);
            mrun[r] = mn;
            rs[r] = 0.f;
        }
        #pragma unroll
        for (int ns = 0; ns < 4; ++ns) {
            #pragma unroll
            for (int r = 0; r < 4; ++r) {
                const float p = exp2f(s[ns][r] - mrun[r]);
                rs[r] += p;
                PO[(quad * 4 + r) * POS + ns * 16 + colid] = f2bf(p);  // C-layout -> row-major
            }
        }
        #pragma unroll
        for (int m = 1; m <= 8; m <<= 1)
            #pragma unroll
            for (int r = 0; r < 4; ++r) rs[r] += __shfl_xor(rs[r], m);
        #pragma unroll
        for (int r = 0; r < 4; ++r) lrun[r] = lrun[r] * alpha[r] + rs[r];
        #pragma unroll
        for (int cs = 0; cs < CS; ++cs)
            #pragma unroll
            for (int r = 0; r < 4; ++r) o[cs][r] *= alpha[r];
        __syncthreads();   // P tile visible (LDS round-trip transpose)

        // ---- O += P @ V ----
        #pragma unroll
        for (int kf2 = 0; kf2 < 2; ++kf2) {
            const short8 pa = *(const short8*)&PO[colid * POS + kf2 * 32 + quad * 8];
            #pragma unroll
            for (int cs = 0; cs < CS; ++cs) {
                const short8 vb = *(const short8*)&Vcol[(cs * 16 + colid) * VST + kf2 * 32 + quad * 8];
                o[cs] = __builtin_amdgcn_mfma_f32_16x16x32_bf16(pa, vb, o[cs], 0, 0, 0);
            }
        }
        __syncthreads();   // all K/V/P reads done before next staging
    }

    // ---- normalize, round-trip O through LDS, project with MFMA ----
    #pragma unroll
    for (int r = 0; r < 4; ++r) lrun[r] = 1.f / lrun[r];
    #pragma unroll
    for (int cs = 0; cs < CS; ++cs)
        #pragma unroll
        for (int r = 0; r < 4; ++r) {
            o[cs][r] *= lrun[r];
            PO[(quad * 4 + r) * POS + cs * 16 + colid] = f2bf(o[cs][r]);
        }
    __syncthreads();

    short8 oa[KF];
    #pragma unroll
    for (int kf = 0; kf < KF; ++kf)
        oa[kf] = *(const short8*)&PO[colid * POS + kf * 32 + quad * 8];

    ushort* Tbuf = Krow;   // reuse (stride 72), Krow dead after main loop
    float rsq[4] = {0.f, 0.f, 0.f, 0.f};
    float msum = 0.f;

    #pragma unroll
    for (int js = 0; js < (HAS_OUT ? 4 : JS); ++js) {
        float v[4];
        if (js < JS) {
            f32x4 acc = (f32x4){0.f, 0.f, 0.f, 0.f};
            #pragma unroll
            for (int kf = 0; kf < KF; ++kf) {
                const short8 wb = *(const short8*)&Wt[(js * 16 + colid) * POS + kf * 32 + quad * 8];
                acc = __builtin_amdgcn_mfma_f32_16x16x32_bf16(oa[kf], wb, acc, 0, 0, 0);
            }
            const float bj = biasS[js * 16 + colid];
            #pragma unroll
            for (int r = 0; r < 4; ++r) v[r] = fmaxf(acc[r] + bj, 0.f);
        } else {
            #pragma unroll
            for (int r = 0; r < 4; ++r) v[r] = 0.f;   // zero-pad cols 48..63
        }
        if (HAS_OUT) {
            #pragma unroll
            for (int r = 0; r < 4; ++r) {
                const int grow = n0blk + w * 16 + quad * 4 + r;
                ho[(size_t)((size_t)b * NN + grow) * 64 + js * 16 + colid] = f2bf(v[r]);
                Tbuf[(js * 16 + colid) * 72 + w * 16 + quad * 4 + r] = f2bf(v[r]);
                rsq[r] += v[r] * v[r];
            }
        }
        if (DO_MEAN) {
            #pragma unroll
            for (int r = 0; r < 4; ++r) msum += v[r];
        }
    }

    if (HAS_OUT) {
        #pragma unroll
        for (int m = 1; m <= 8; m <<= 1)
            #pragma unroll
            for (int r = 0; r < 4; ++r) rsq[r] += __shfl_xor(rsq[r], m);
        if (colid == 0) {
            #pragma unroll
            for (int r = 0; r < 4; ++r)
                sqo[(size_t)b * NN + n0blk + w * 16 + quad * 4 + r] = rsq[r];
        }
        __syncthreads();
        // coalesced transposed store: hoT[b][c][n]
        for (int id = t; id < 64 * 8; id += 256) {
            const int row = id >> 3, part = id & 7;
            *(short8*)&hoT[((size_t)b * 64 + row) * NN + n0blk + part * 8] =
                *(const short8*)&Tbuf[row * 72 + part * 8];
        }
    }
    if (DO_MEAN) {
        msum += __shfl_xor(msum, 16);
        msum += __shfl_xor(msum, 32);
        if (lane < C_OUT) atomicAdd(&mean_out[b * C_OUT + lane], msum * (1.f / NN));
    }
}

// ---------------------------------------------------------------------------
// Final classifier + softmax over 2 logits. 64 threads = 32 batches x 2.
// ---------------------------------------------------------------------------
__global__ __launch_bounds__(64) void final_kernel(
    const float* __restrict__ mean, const float* __restrict__ Wf,
    const float* __restrict__ bf, float* __restrict__ out)
{
    const int t = threadIdx.x;
    const int b = t >> 1, k = t & 1;
    float acc = bf[k];
    #pragma unroll
    for (int c = 0; c < H4; ++c) acc += mean[b * H4 + c] * Wf[c * 2 + k];
    const float other = __shfl_xor(acc, 1);
    const float mx = fmaxf(acc, other);
    const float e  = __expf(acc - mx);
    const float eo = __expf(other - mx);
    out[t] = e / (e + eo);
}

extern "C" void kernel_launch(void* const* d_in, const int* in_sizes, int n_in,
                              void* d_out, int out_size, void* d_ws, size_t ws_size,
                              hipStream_t stream) {
    const float* x   = (const float*)d_in[0];
    const float* W1  = (const float*)d_in[1];
    const float* b1  = (const float*)d_in[2];
    const float* W2  = (const float*)d_in[3];
    const float* b2  = (const float*)d_in[4];
    const float* Wg1 = (const float*)d_in[5];
    const float* bg1 = (const float*)d_in[6];
    const float* Wg2 = (const float*)d_in[7];
    const float* bg2 = (const float*)d_in[8];
    const float* Wf  = (const float*)d_in[9];
    const float* bf  = (const float*)d_in[10];

    ushort* h2  = (ushort*)d_ws;                         // [B*N][96] bf16
    ushort* h2T = h2  + (size_t)BB * NN * 96;            // [B][96][N] bf16
    float*  sq2 = (float*)(h2T + (size_t)BB * 96 * NN);  // [B*N]
    ushort* h3  = (ushort*)(sq2 + (size_t)BB * NN);      // [B*N][64] bf16
    ushort* h3T = h3  + (size_t)BB * NN * 64;            // [B][64][N] bf16
    float*  sq3 = (float*)(h3T + (size_t)BB * 64 * NN);  // [B*N]
    float*  meanb = sq3 + (size_t)BB * NN;               // [B*5]

    hipMemsetAsync(meanb, 0, BB * H4 * sizeof(float), stream);

    mlp_kernel<<<BB * NN / 8, 320, 0, stream>>>(x, W1, b1, W2, b2, h2, h2T, sq2);
    attn_conv_kernel<96, 80, 40, 3, true,  false><<<BB * NN / 64, 256, 0, stream>>>(
        h2, h2T, sq2, Wg1, bg1, h3, h3T, sq3, nullptr);
    attn_conv_kernel<64, 40, 5, 1, false, true><<<BB * NN / 64, 256, 0, stream>>>(
        h3, h3T, sq3, Wg2, bg2, nullptr, nullptr, nullptr, meanb);
    final_kernel<<<1, 64, 0, stream>>>(meanb, Wf, bf, (float*)d_out);
}

// Round 3
// 549.452 us; speedup vs baseline: 11.1817x; 1.3287x over previous
//
#include <hip/hip_runtime.h>
#include <math.h>

#define BB 32
#define NN 2048
#define D_IN 320
#define H1 160
#define H2 80
#define H4 5

typedef __attribute__((ext_vector_type(8))) short short8;
typedef __attribute__((ext_vector_type(4))) float f32x4;

__device__ inline ushort f2bf(float f) {
    union { float f; unsigned u; } v; v.f = f;
    unsigned r = v.u + 0x7fff + ((v.u >> 16) & 1);   // RNE; inputs never NaN here
    return (ushort)(r >> 16);
}
__device__ inline float bf2f(ushort u) {
    union { float f; unsigned u; } v; v.u = ((unsigned)u) << 16;
    return v.f;
}

// ---------------------------------------------------------------------------
// MLP: h2 = relu(relu(x@W1+b1)@W2+b2). 8 rows/block, 320 threads.
// Emits bf16 h2 padded to 96 ch, bf16 h2T [b][96][N], and sq2 = |bf16(h2)|^2.
// ---------------------------------------------------------------------------
__global__ __launch_bounds__(320) void mlp_kernel(
    const float* __restrict__ x,  const float* __restrict__ W1, const float* __restrict__ b1,
    const float* __restrict__ W2, const float* __restrict__ b2,
    ushort* __restrict__ h2, ushort* __restrict__ h2T, float* __restrict__ sq2)
{
    __shared__ float xs[8][D_IN];
    __shared__ float h1s[8][H1];
    __shared__ float o2[8][H2];

    const int t = threadIdx.x;
    const int row0 = blockIdx.x * 8;

    #pragma unroll
    for (int i = 0; i < 8; ++i) xs[i][t] = x[(size_t)(row0 + i) * D_IN + t];
    __syncthreads();

    { // layer 1: 320 threads = (half 0..1) x (j 0..159), 4 rows each
        const int j = t % H1, half = t / H1;
        float a0 = b1[j], a1 = a0, a2 = a0, a3 = a0;
        for (int c = 0; c < D_IN; ++c) {
            const float wv = W1[c * H1 + j];
            a0 = fmaf(xs[half*4+0][c], wv, a0);
            a1 = fmaf(xs[half*4+1][c], wv, a1);
            a2 = fmaf(xs[half*4+2][c], wv, a2);
            a3 = fmaf(xs[half*4+3][c], wv, a3);
        }
        h1s[half*4+0][j] = fmaxf(a0, 0.f);
        h1s[half*4+1][j] = fmaxf(a1, 0.f);
        h1s[half*4+2][j] = fmaxf(a2, 0.f);
        h1s[half*4+3][j] = fmaxf(a3, 0.f);
    }
    __syncthreads();

    const int b = row0 / NN, n = row0 % NN;
    { // layer 2: (g 0..3) x (k 0..79), rows g and g+4
        const int k = t % H2, g = t / H2;
        float c0 = b2[k], c1 = b2[k];
        for (int j = 0; j < H1; ++j) {
            const float wv = W2[j * H2 + k];
            c0 = fmaf(h1s[g][j],     wv, c0);
            c1 = fmaf(h1s[g + 4][j], wv, c1);
        }
        const ushort u0 = f2bf(fmaxf(c0, 0.f));
        const ushort u1 = f2bf(fmaxf(c1, 0.f));
        o2[g][k]     = bf2f(u0);            // rounded values -> consistent sq
        o2[g + 4][k] = bf2f(u1);
        h2[(size_t)(row0 + g)     * 96 + k] = u0;
        h2[(size_t)(row0 + g + 4) * 96 + k] = u1;
        h2T[((size_t)b * 96 + k) * NN + n + g]     = u0;
        h2T[((size_t)b * 96 + k) * NN + n + g + 4] = u1;
    }
    // zero channel pads (80..95) in both layouts
    if (t < 128) {
        const int r = t >> 4, c = 80 + (t & 15);
        h2[(size_t)(row0 + r) * 96 + c] = 0;
    }
    if (t < 128) {
        const int c = 80 + (t >> 3), nn2 = t & 7;
        h2T[((size_t)b * 96 + c) * NN + n + nn2] = 0;
    }
    __syncthreads();
    if (t < 8) {
        float s = 0.f;
        for (int k = 0; k < H2; ++k) s += o2[t][k] * o2[t][k];
        sq2[row0 + t] = s;
    }
}

// ---------------------------------------------------------------------------
// Flash-attention graph conv on bf16 MFMA 16x16x32.
//   s = 2*h_n.h_m - |h_m|^2 = |h_n|^2 - |h_n - h_m|^2  =>  row max == |h_n|^2
//   (achieved at m==n), so NO max reduction / online rescaling is needed:
//   p = exp(s - |h_n|^2), l accumulated per-lane, reduced once at the end.
// Block: 256 thr / 4 waves; 64 Q-rows per block (16 per wave); keys in 64-chunks.
// ---------------------------------------------------------------------------
template<int C_PAD, int C_IN_REAL, int C_OUT, int JS, bool HAS_OUT, bool DO_MEAN>
__global__ __launch_bounds__(256) void attn_conv_kernel(
    const ushort* __restrict__ h, const ushort* __restrict__ hT,
    const float* __restrict__ sqg,
    const float* __restrict__ W, const float* __restrict__ bias,
    ushort* __restrict__ ho, ushort* __restrict__ hoT, float* __restrict__ sqo,
    float* __restrict__ mean_out)
{
    constexpr int KF  = C_PAD / 32;      // k-frags per 32-chunk (3 or 2)
    constexpr int CS  = C_PAD / 16;      // O column subtiles (6 or 4)
    constexpr int KST = C_PAD + 8;       // Krow LDS stride (bf16)
    constexpr int VST = 64 + 8;          // Vcol LDS stride
    constexpr int POS = C_PAD + 8;       // P/O transpose buffer stride
    constexpr int NKLD = (64 * C_PAD / 8) / 256;  // short8 K-loads per thread
    constexpr int NVLD = (C_PAD * 8) / 256;       // short8 V-loads per thread

    __shared__ __attribute__((aligned(16))) ushort Krow[64 * KST];
    __shared__ __attribute__((aligned(16))) ushort Vcol[C_PAD * VST];
    __shared__ __attribute__((aligned(16))) ushort PObuf[4 * 16 * POS];
    __shared__ __attribute__((aligned(16))) ushort Wt[JS * 16 * POS];
    __shared__ float biasS[JS * 16];
    __shared__ float sqs[64];

    const int t = threadIdx.x;
    const int lane = t & 63, w = t >> 6;
    const int colid = lane & 15, quad = lane >> 4;
    const int b = blockIdx.x >> 5;             // NN/64 = 32 row-tiles per batch
    const int n0blk = (blockIdx.x & 31) * 64;

    const float LOG2E  = 1.44269504088896340736f;
    const float TWOL2E = 2.88539008177792681472f;

    // stage W^T (bf16, zero-padded) + bias, resident for the whole block
    for (int id = t; id < JS * 16 * C_PAD; id += 256) {
        const int j = id / C_PAD, c = id % C_PAD;
        const float v = (j < C_OUT && c < C_IN_REAL) ? W[c * C_OUT + j] : 0.f;
        Wt[j * POS + c] = f2bf(v);
    }
    if (t < JS * 16) biasS[t] = (t < C_OUT) ? bias[t] : 0.f;

    // Q A-frags: lane holds Q[m=lane&15][k=quad*8+j]  (m120-verified layout)
    short8 qf[KF];
    {
        const ushort* qrow = h + (size_t)((size_t)b * NN + n0blk + w * 16 + colid) * C_PAD;
        #pragma unroll
        for (int kf = 0; kf < KF; ++kf)
            qf[kf] = *(const short8*)&qrow[kf * 32 + quad * 8];
    }

    // per-lane row biases: |h_n|^2 * log2(e) for rows quad*4+r
    float sqnL[4];
    #pragma unroll
    for (int r = 0; r < 4; ++r)
        sqnL[r] = sqg[(size_t)b * NN + n0blk + w * 16 + quad * 4 + r] * LOG2E;

    f32x4 o[CS];
    #pragma unroll
    for (int cs = 0; cs < CS; ++cs) o[cs] = (f32x4){0.f, 0.f, 0.f, 0.f};
    float rs[4] = {0.f, 0.f, 0.f, 0.f};       // per-lane softmax denominator parts

    ushort* PO = PObuf + w * 16 * POS;

    // prefetch tile 0 into registers
    short8 kreg[NKLD], vreg[NVLD];
    float sqreg = 0.f;
    {
        const ushort* hsrc = h + (size_t)((size_t)b * NN) * C_PAD;
        #pragma unroll
        for (int i = 0; i < NKLD; ++i)
            kreg[i] = *(const short8*)&hsrc[(t + i * 256) * 8];
        #pragma unroll
        for (int i = 0; i < NVLD; ++i) {
            const int id = t + i * 256, c = id >> 3, pt = id & 7;
            vreg[i] = *(const short8*)&hT[((size_t)b * C_PAD + c) * NN + pt * 8];
        }
        if (t < 64) sqreg = sqg[(size_t)b * NN + t];
    }

    for (int n0 = 0; n0 < NN; n0 += 64) {
        // ---- commit prefetched tile to LDS, prefetch next ----
        if (n0) __syncthreads();               // prev readers done
        #pragma unroll
        for (int i = 0; i < NKLD; ++i) {
            const int id = t + i * 256;
            const int row = id / (C_PAD / 8), pt = id % (C_PAD / 8);
            *(short8*)&Krow[row * KST + pt * 8] = kreg[i];
        }
        #pragma unroll
        for (int i = 0; i < NVLD; ++i) {
            const int id = t + i * 256, c = id >> 3, pt = id & 7;
            *(short8*)&Vcol[c * VST + pt * 8] = vreg[i];
        }
        if (t < 64) sqs[t] = sqreg;
        if (n0 + 64 < NN) {                    // loads land during compute
            const int n1 = n0 + 64;
            const ushort* hsrc = h + (size_t)((size_t)b * NN + n1) * C_PAD;
            #pragma unroll
            for (int i = 0; i < NKLD; ++i)
                kreg[i] = *(const short8*)&hsrc[(t + i * 256) * 8];
            #pragma unroll
            for (int i = 0; i < NVLD; ++i) {
                const int id = t + i * 256, c = id >> 3, pt = id & 7;
                vreg[i] = *(const short8*)&hT[((size_t)b * C_PAD + c) * NN + n1 + pt * 8];
            }
            if (t < 64) sqreg = sqg[(size_t)b * NN + n1 + t];
        }
        __syncthreads();                       // tile visible

        // ---- S = Q.K^T, 4 col-subtiles of 16 ----
        f32x4 s[4];
        #pragma unroll
        for (int ns = 0; ns < 4; ++ns) {
            f32x4 acc = (f32x4){0.f, 0.f, 0.f, 0.f};
            #pragma unroll
            for (int kf = 0; kf < KF; ++kf) {
                const short8 bf = *(const short8*)&Krow[(ns * 16 + colid) * KST + kf * 32 + quad * 8];
                acc = __builtin_amdgcn_mfma_f32_16x16x32_bf16(qf[kf], bf, acc, 0, 0, 0);
            }
            s[ns] = acc;
        }

        // ---- p = exp2((2*s - sq_m - sq_n) * log2e); no reductions ----
        #pragma unroll
        for (int ns = 0; ns < 4; ++ns) {
            const float bmL = sqs[ns * 16 + colid] * LOG2E;
            #pragma unroll
            for (int r = 0; r < 4; ++r) {
                const float p = exp2f(fmaf(s[ns][r], TWOL2E, -(bmL + sqnL[r])));
                rs[r] += p;
                PO[(quad * 4 + r) * POS + ns * 16 + colid] = f2bf(p);
            }
        }
        // PO is wave-private: same-wave write->read needs only lgkmcnt(0)
        __asm__ volatile("s_waitcnt lgkmcnt(0)" ::: "memory");

        // ---- O += P @ V ----
        #pragma unroll
        for (int kf2 = 0; kf2 < 2; ++kf2) {
            const short8 pa = *(const short8*)&PO[colid * POS + kf2 * 32 + quad * 8];
            #pragma unroll
            for (int cs = 0; cs < CS; ++cs) {
                const short8 vb = *(const short8*)&Vcol[(cs * 16 + colid) * VST + kf2 * 32 + quad * 8];
                o[cs] = __builtin_amdgcn_mfma_f32_16x16x32_bf16(pa, vb, o[cs], 0, 0, 0);
            }
        }
    }
    __syncthreads();                           // Krow free for reuse as Tbuf

    // ---- denominator: reduce per-lane parts across the 16 cols ----
    #pragma unroll
    for (int m = 1; m <= 8; m <<= 1)
        #pragma unroll
        for (int r = 0; r < 4; ++r) rs[r] += __shfl_xor(rs[r], m);
    #pragma unroll
    for (int r = 0; r < 4; ++r) rs[r] = 1.f / rs[r];

    // ---- normalize, round-trip O through LDS, project with MFMA ----
    #pragma unroll
    for (int cs = 0; cs < CS; ++cs)
        #pragma unroll
        for (int r = 0; r < 4; ++r)
            PO[(quad * 4 + r) * POS + cs * 16 + colid] = f2bf(o[cs][r] * rs[r]);
    __asm__ volatile("s_waitcnt lgkmcnt(0)" ::: "memory");

    short8 oa[KF];
    #pragma unroll
    for (int kf = 0; kf < KF; ++kf)
        oa[kf] = *(const short8*)&PO[colid * POS + kf * 32 + quad * 8];

    ushort* Tbuf = Krow;   // reuse (stride 72), Krow dead after main loop
    float rsq[4] = {0.f, 0.f, 0.f, 0.f};
    float msum = 0.f;

    #pragma unroll
    for (int js = 0; js < (HAS_OUT ? 4 : JS); ++js) {
        float v[4];
        if (js < JS) {
            f32x4 acc = (f32x4){0.f, 0.f, 0.f, 0.f};
            #pragma unroll
            for (int kf = 0; kf < KF; ++kf) {
                const short8 wb = *(const short8*)&Wt[(js * 16 + colid) * POS + kf * 32 + quad * 8];
                acc = __builtin_amdgcn_mfma_f32_16x16x32_bf16(oa[kf], wb, acc, 0, 0, 0);
            }
            const float bj = biasS[js * 16 + colid];
            #pragma unroll
            for (int r = 0; r < 4; ++r) v[r] = fmaxf(acc[r] + bj, 0.f);
        } else {
            #pragma unroll
            for (int r = 0; r < 4; ++r) v[r] = 0.f;   // zero-pad cols 48..63
        }
        if (HAS_OUT) {
            #pragma unroll
            for (int r = 0; r < 4; ++r) {
                const int grow = n0blk + w * 16 + quad * 4 + r;
                ho[(size_t)((size_t)b * NN + grow) * 64 + js * 16 + colid] = f2bf(v[r]);
                Tbuf[(js * 16 + colid) * 72 + w * 16 + quad * 4 + r] = f2bf(v[r]);
                rsq[r] += v[r] * v[r];
            }
        }
        if (DO_MEAN) {
            #pragma unroll
            for (int r = 0; r < 4; ++r) msum += v[r];
        }
    }

    if (HAS_OUT) {
        #pragma unroll
        for (int m = 1; m <= 8; m <<= 1)
            #pragma unroll
            for (int r = 0; r < 4; ++r) rsq[r] += __shfl_xor(rsq[r], m);
        if (colid == 0) {
            #pragma unroll
            for (int r = 0; r < 4; ++r)
                sqo[(size_t)b * NN + n0blk + w * 16 + quad * 4 + r] = rsq[r];
        }
        __syncthreads();
        // coalesced transposed store: hoT[b][c][n]
        for (int id = t; id < 64 * 8; id += 256) {
            const int row = id >> 3, part = id & 7;
            *(short8*)&hoT[((size_t)b * 64 + row) * NN + n0blk + part * 8] =
                *(const short8*)&Tbuf[row * 72 + part * 8];
        }
    }
    if (DO_MEAN) {
        msum += __shfl_xor(msum, 16);
        msum += __shfl_xor(msum, 32);
        if (lane < C_OUT) atomicAdd(&mean_out[b * C_OUT + lane], msum * (1.f / NN));
    }
}

// ---------------------------------------------------------------------------
// Final classifier + softmax over 2 logits. 64 threads = 32 batches x 2.
// ---------------------------------------------------------------------------
__global__ __launch_bounds__(64) void final_kernel(
    const float* __restrict__ mean, const float* __restrict__ Wf,
    const float* __restrict__ bf, float* __restrict__ out)
{
    const int t = threadIdx.x;
    const int b = t >> 1, k = t & 1;
    float acc = bf[k];
    #pragma unroll
    for (int c = 0; c < H4; ++c) acc += mean[b * H4 + c] * Wf[c * 2 + k];
    const float other = __shfl_xor(acc, 1);
    const float mx = fmaxf(acc, other);
    const float e  = __expf(acc - mx);
    const float eo = __expf(other - mx);
    out[t] = e / (e + eo);
}

extern "C" void kernel_launch(void* const* d_in, const int* in_sizes, int n_in,
                              void* d_out, int out_size, void* d_ws, size_t ws_size,
                              hipStream_t stream) {
    const float* x   = (const float*)d_in[0];
    const float* W1  = (const float*)d_in[1];
    const float* b1  = (const float*)d_in[2];
    const float* W2  = (const float*)d_in[3];
    const float* b2  = (const float*)d_in[4];
    const float* Wg1 = (const float*)d_in[5];
    const float* bg1 = (const float*)d_in[6];
    const float* Wg2 = (const float*)d_in[7];
    const float* bg2 = (const float*)d_in[8];
    const float* Wf  = (const float*)d_in[9];
    const float* bf  = (const float*)d_in[10];

    ushort* h2  = (ushort*)d_ws;                         // [B*N][96] bf16
    ushort* h2T = h2  + (size_t)BB * NN * 96;            // [B][96][N] bf16
    float*  sq2 = (float*)(h2T + (size_t)BB * 96 * NN);  // [B*N]
    ushort* h3  = (ushort*)(sq2 + (size_t)BB * NN);      // [B*N][64] bf16
    ushort* h3T = h3  + (size_t)BB * NN * 64;            // [B][64][N] bf16
    float*  sq3 = (float*)(h3T + (size_t)BB * 64 * NN);  // [B*N]
    float*  meanb = sq3 + (size_t)BB * NN;               // [B*5]

    hipMemsetAsync(meanb, 0, BB * H4 * sizeof(float), stream);

    mlp_kernel<<<BB * NN / 8, 320, 0, stream>>>(x, W1, b1, W2, b2, h2, h2T, sq2);
    attn_conv_kernel<96, 80, 40, 3, true,  false><<<BB * NN / 64, 256, 0, stream>>>(
        h2, h2T, sq2, Wg1, bg1, h3, h3T, sq3, nullptr);
    attn_conv_kernel<64, 40, 5, 1, false, true><<<BB * NN / 64, 256, 0, stream>>>(
        h3, h3T, sq3, Wg2, bg2, nullptr, nullptr, nullptr, meanb);
    final_kernel<<<1, 64, 0, stream>>>(meanb, Wf, bf, (float*)d_out);
}

// Round 4
// 371.916 us; speedup vs baseline: 16.5193x; 1.4774x over previous
//
#include <hip/hip_runtime.h>
#include <math.h>

#define BB 32
#define NN 2048
#define D_IN 320
#define H1 160
#define H2 80
#define H4 5

typedef __attribute__((ext_vector_type(8))) short short8;
typedef __attribute__((ext_vector_type(4))) short short4v;
typedef __attribute__((ext_vector_type(4))) float f32x4;

__device__ inline ushort f2bf(float f) {
    union { float f; unsigned u; } v; v.f = f;
    unsigned r = v.u + 0x7fff + ((v.u >> 16) & 1);   // RNE; inputs never NaN here
    return (ushort)(r >> 16);
}
__device__ inline float bf2f(ushort u) {
    union { float f; unsigned u; } v; v.u = ((unsigned)u) << 16;
    return v.f;
}

// ---------------------------------------------------------------------------
// Prep: transpose W1/W2 to bf16  Wt1[j=160][c=320], Wt2[j=80][c=160].
// Tiny (64K elems); runs once before the MLP.
// ---------------------------------------------------------------------------
__global__ __launch_bounds__(256) void prep_weights_kernel(
    const float* __restrict__ W1, const float* __restrict__ W2,
    ushort* __restrict__ Wt1, ushort* __restrict__ Wt2)
{
    const int id0 = blockIdx.x * 256 + threadIdx.x;
    const int stride = gridDim.x * 256;
    for (int i = id0; i < H1 * D_IN; i += stride) {
        const int j = i / D_IN, c = i % D_IN;
        Wt1[i] = f2bf(W1[c * H1 + j]);
    }
    for (int i = id0; i < H2 * H1; i += stride) {
        const int j = i / H1, c = i % H1;
        Wt2[i] = f2bf(W2[c * H2 + j]);
    }
}

// ---------------------------------------------------------------------------
// MFMA MLP: h2 = relu(relu(x@W1+b1)@W2+b2), bf16 16x16x32 MFMA.
// 64 rows/block, 256 thr / 4 waves (16 rows each). K-chunked layer 1 with
// register prefetch; block-resident Wt2 for layer 2. Emits bf16 h2 (pad 96),
// h2T [b][96][N], sq2 = |bf16(h2)|^2.
// ---------------------------------------------------------------------------
__global__ __launch_bounds__(256) void mlp_mfma_kernel(
    const float* __restrict__ x,
    const ushort* __restrict__ Wt1, const float* __restrict__ b1,
    const ushort* __restrict__ Wt2, const float* __restrict__ b2,
    ushort* __restrict__ h2, ushort* __restrict__ h2T, float* __restrict__ sq2)
{
    constexpr int XST  = 72;    // x-tile LDS stride (64 k + 8 pad), bf16
    constexpr int W1ST = 72;    // Wt1-chunk stride
    constexpr int W2ST = 168;   // Wt2 stride (160 + 8)
    constexpr int H1ST = 168;   // h1-tile stride

    __shared__ __attribute__((aligned(16))) ushort h1t[64 * H1ST];  // aliases xs
    __shared__ __attribute__((aligned(16))) ushort ws1[H1 * W1ST];  // aliases Tbuf
    __shared__ __attribute__((aligned(16))) ushort ws2[H2 * W2ST];
    __shared__ float b1s[H1];
    __shared__ float b2s[H2];

    ushort* xs = h1t;           // [64][XST] during the k-chunk loop (dead after)

    const int t = threadIdx.x;
    const int lane = t & 63, w = t >> 6;
    const int colid = lane & 15, quad = lane >> 4;
    const int row0 = blockIdx.x * 64;
    const int b = row0 / NN, n0 = row0 % NN;

    if (t < H1) b1s[t] = b1[t];
    if (t < H2) b2s[t] = b2[t];

    // stage Wt2 (block-resident): 80 x 160 bf16
    for (int id = t; id < H2 * H1 / 8; id += 256) {
        const int j = id / 20, part = id % 20;
        *(short8*)&ws2[j * W2ST + part * 8] = *(const short8*)&Wt2[j * H1 + part * 8];
    }

    f32x4 c1[10];
    #pragma unroll
    for (int ns = 0; ns < 10; ++ns) c1[ns] = (f32x4){0.f, 0.f, 0.f, 0.f};

    // prefetch chunk 0
    float4 xr[4];
    short8 wr[5];
    {
        #pragma unroll
        for (int i = 0; i < 4; ++i) {
            const int id = t + i * 256, row = id >> 4, c4 = id & 15;
            xr[i] = *(const float4*)&x[(size_t)(row0 + row) * D_IN + c4 * 4];
        }
        #pragma unroll
        for (int i = 0; i < 5; ++i) {
            const int id = t + i * 256, j = id >> 3, part = id & 7;
            wr[i] = *(const short8*)&Wt1[j * D_IN + part * 8];
        }
    }

    for (int kc = 0; kc < 5; ++kc) {
        if (kc) __syncthreads();               // prev chunk readers done
        #pragma unroll
        for (int i = 0; i < 4; ++i) {
            const int id = t + i * 256, row = id >> 4, c4 = id & 15;
            short4v s;
            s[0] = (short)f2bf(xr[i].x); s[1] = (short)f2bf(xr[i].y);
            s[2] = (short)f2bf(xr[i].z); s[3] = (short)f2bf(xr[i].w);
            *(short4v*)&xs[row * XST + c4 * 4] = s;
        }
        #pragma unroll
        for (int i = 0; i < 5; ++i) {
            const int id = t + i * 256, j = id >> 3, part = id & 7;
            *(short8*)&ws1[j * W1ST + part * 8] = wr[i];
        }
        if (kc < 4) {                          // prefetch next chunk
            const int k0 = (kc + 1) * 64;
            #pragma unroll
            for (int i = 0; i < 4; ++i) {
                const int id = t + i * 256, row = id >> 4, c4 = id & 15;
                xr[i] = *(const float4*)&x[(size_t)(row0 + row) * D_IN + k0 + c4 * 4];
            }
            #pragma unroll
            for (int i = 0; i < 5; ++i) {
                const int id = t + i * 256, j = id >> 3, part = id & 7;
                wr[i] = *(const short8*)&Wt1[j * D_IN + k0 + part * 8];
            }
        }
        __syncthreads();                       // tile visible

        short8 af[2];
        #pragma unroll
        for (int kf = 0; kf < 2; ++kf)
            af[kf] = *(const short8*)&xs[(w * 16 + colid) * XST + kf * 32 + quad * 8];
        #pragma unroll
        for (int ns = 0; ns < 10; ++ns) {
            #pragma unroll
            for (int kf = 0; kf < 2; ++kf) {
                const short8 bf = *(const short8*)&ws1[(ns * 16 + colid) * W1ST + kf * 32 + quad * 8];
                c1[ns] = __builtin_amdgcn_mfma_f32_16x16x32_bf16(af[kf], bf, c1[ns], 0, 0, 0);
            }
        }
    }
    __syncthreads();                           // xs fully dead -> h1t reuse safe

    // relu + bias -> h1 tile (wave-private rows)
    #pragma unroll
    for (int ns = 0; ns < 10; ++ns) {
        const float bj = b1s[ns * 16 + colid];
        #pragma unroll
        for (int r = 0; r < 4; ++r)
            h1t[(w * 16 + quad * 4 + r) * H1ST + ns * 16 + colid] =
                f2bf(fmaxf(c1[ns][r] + bj, 0.f));
    }
    __asm__ volatile("s_waitcnt lgkmcnt(0)" ::: "memory");  // same-wave write->read

    // layer 2: 16x80 per wave, K=160
    short8 a2[5];
    #pragma unroll
    for (int kf = 0; kf < 5; ++kf)
        a2[kf] = *(const short8*)&h1t[(w * 16 + colid) * H1ST + kf * 32 + quad * 8];

    f32x4 c2[5];
    #pragma unroll
    for (int js = 0; js < 5; ++js) {
        f32x4 acc = (f32x4){0.f, 0.f, 0.f, 0.f};
        #pragma unroll
        for (int kf = 0; kf < 5; ++kf) {
            const short8 wb = *(const short8*)&ws2[(js * 16 + colid) * W2ST + kf * 32 + quad * 8];
            acc = __builtin_amdgcn_mfma_f32_16x16x32_bf16(a2[kf], wb, acc, 0, 0, 0);
        }
        c2[js] = acc;
    }
    __syncthreads();                           // ws1 dead -> Tbuf reuse safe

    // epilogue: relu+bias, h2 (row-major, pad 96), Tbuf transpose, sq
    ushort* Tbuf = ws1;                        // [96][72]
    float rsq[4] = {0.f, 0.f, 0.f, 0.f};
    #pragma unroll
    for (int js = 0; js < 5; ++js) {
        const float bj = b2s[js * 16 + colid];
        #pragma unroll
        for (int r = 0; r < 4; ++r) {
            const ushort u = f2bf(fmaxf(c2[js][r] + bj, 0.f));
            const float vv = bf2f(u);
            rsq[r] += vv * vv;
            h2[(size_t)(row0 + w * 16 + quad * 4 + r) * 96 + js * 16 + colid] = u;
            Tbuf[(js * 16 + colid) * 72 + w * 16 + quad * 4 + r] = u;
        }
    }
    // zero pads: h2 cols 80..95, Tbuf rows 80..95
    {
        const short8 z8 = {0, 0, 0, 0, 0, 0, 0, 0};
        if (t < 128) {
            const int row = t >> 1, part = t & 1;
            *(short8*)&h2[(size_t)(row0 + row) * 96 + 80 + part * 8] = z8;
        }
        if (t < 128) {
            const int row = 80 + (t >> 3), part = t & 7;
            *(short8*)&Tbuf[row * 72 + part * 8] = z8;
        }
    }
    // sq2: reduce across the 16 cols held per lane-group
    #pragma unroll
    for (int m = 1; m <= 8; m <<= 1)
        #pragma unroll
        for (int r = 0; r < 4; ++r) rsq[r] += __shfl_xor(rsq[r], m);
    if (colid == 0) {
        #pragma unroll
        for (int r = 0; r < 4; ++r)
            sq2[(size_t)row0 + w * 16 + quad * 4 + r] = rsq[r];
    }
    __syncthreads();
    // coalesced transposed store: h2T[b][c][n0..n0+64]
    for (int id = t; id < 96 * 8; id += 256) {
        const int row = id >> 3, part = id & 7;
        *(short8*)&h2T[((size_t)b * 96 + row) * NN + n0 + part * 8] =
            *(const short8*)&Tbuf[row * 72 + part * 8];
    }
}

// ---------------------------------------------------------------------------
// Flash-attention graph conv on bf16 MFMA 16x16x32.
//   s = 2*h_n.h_m - |h_m|^2 = |h_n|^2 - |h_n - h_m|^2  =>  row max == |h_n|^2
//   (achieved at m==n), so NO max reduction / online rescaling is needed:
//   p = exp(s - |h_n|^2), l accumulated per-lane, reduced once at the end.
// Block: 256 thr / 4 waves; 64 Q-rows per block (16 per wave); keys in 64-chunks.
// ---------------------------------------------------------------------------
template<int C_PAD, int C_IN_REAL, int C_OUT, int JS, bool HAS_OUT, bool DO_MEAN>
__global__ __launch_bounds__(256) void attn_conv_kernel(
    const ushort* __restrict__ h, const ushort* __restrict__ hT,
    const float* __restrict__ sqg,
    const float* __restrict__ W, const float* __restrict__ bias,
    ushort* __restrict__ ho, ushort* __restrict__ hoT, float* __restrict__ sqo,
    float* __restrict__ mean_out)
{
    constexpr int KF  = C_PAD / 32;      // k-frags per 32-chunk (3 or 2)
    constexpr int CS  = C_PAD / 16;      // O column subtiles (6 or 4)
    constexpr int KST = C_PAD + 8;       // Krow LDS stride (bf16)
    constexpr int VST = 64 + 8;          // Vcol LDS stride
    constexpr int POS = C_PAD + 8;       // P/O transpose buffer stride
    constexpr int NKLD = (64 * C_PAD / 8) / 256;  // short8 K-loads per thread
    constexpr int NVLD = (C_PAD * 8) / 256;       // short8 V-loads per thread

    __shared__ __attribute__((aligned(16))) ushort Krow[64 * KST];
    __shared__ __attribute__((aligned(16))) ushort Vcol[C_PAD * VST];
    __shared__ __attribute__((aligned(16))) ushort PObuf[4 * 16 * POS];
    __shared__ __attribute__((aligned(16))) ushort Wt[JS * 16 * POS];
    __shared__ float biasS[JS * 16];
    __shared__ float sqs[64];

    const int t = threadIdx.x;
    const int lane = t & 63, w = t >> 6;
    const int colid = lane & 15, quad = lane >> 4;
    const int b = blockIdx.x >> 5;             // NN/64 = 32 row-tiles per batch
    const int n0blk = (blockIdx.x & 31) * 64;

    const float LOG2E  = 1.44269504088896340736f;
    const float TWOL2E = 2.88539008177792681472f;

    // stage W^T (bf16, zero-padded) + bias, resident for the whole block
    for (int id = t; id < JS * 16 * C_PAD; id += 256) {
        const int j = id / C_PAD, c = id % C_PAD;
        const float v = (j < C_OUT && c < C_IN_REAL) ? W[c * C_OUT + j] : 0.f;
        Wt[j * POS + c] = f2bf(v);
    }
    if (t < JS * 16) biasS[t] = (t < C_OUT) ? bias[t] : 0.f;

    // Q A-frags: lane holds Q[m=lane&15][k=quad*8+j]  (m120-verified layout)
    short8 qf[KF];
    {
        const ushort* qrow = h + (size_t)((size_t)b * NN + n0blk + w * 16 + colid) * C_PAD;
        #pragma unroll
        for (int kf = 0; kf < KF; ++kf)
            qf[kf] = *(const short8*)&qrow[kf * 32 + quad * 8];
    }

    // per-lane row biases: |h_n|^2 * log2(e) for rows quad*4+r
    float sqnL[4];
    #pragma unroll
    for (int r = 0; r < 4; ++r)
        sqnL[r] = sqg[(size_t)b * NN + n0blk + w * 16 + quad * 4 + r] * LOG2E;

    f32x4 o[CS];
    #pragma unroll
    for (int cs = 0; cs < CS; ++cs) o[cs] = (f32x4){0.f, 0.f, 0.f, 0.f};
    float rs[4] = {0.f, 0.f, 0.f, 0.f};       // per-lane softmax denominator parts

    ushort* PO = PObuf + w * 16 * POS;

    // prefetch tile 0 into registers
    short8 kreg[NKLD], vreg[NVLD];
    float sqreg = 0.f;
    {
        const ushort* hsrc = h + (size_t)((size_t)b * NN) * C_PAD;
        #pragma unroll
        for (int i = 0; i < NKLD; ++i)
            kreg[i] = *(const short8*)&hsrc[(t + i * 256) * 8];
        #pragma unroll
        for (int i = 0; i < NVLD; ++i) {
            const int id = t + i * 256, c = id >> 3, pt = id & 7;
            vreg[i] = *(const short8*)&hT[((size_t)b * C_PAD + c) * NN + pt * 8];
        }
        if (t < 64) sqreg = sqg[(size_t)b * NN + t];
    }

    for (int n0 = 0; n0 < NN; n0 += 64) {
        // ---- commit prefetched tile to LDS, prefetch next ----
        if (n0) __syncthreads();               // prev readers done
        #pragma unroll
        for (int i = 0; i < NKLD; ++i) {
            const int id = t + i * 256;
            const int row = id / (C_PAD / 8), pt = id % (C_PAD / 8);
            *(short8*)&Krow[row * KST + pt * 8] = kreg[i];
        }
        #pragma unroll
        for (int i = 0; i < NVLD; ++i) {
            const int id = t + i * 256, c = id >> 3, pt = id & 7;
            *(short8*)&Vcol[c * VST + pt * 8] = vreg[i];
        }
        if (t < 64) sqs[t] = sqreg;
        if (n0 + 64 < NN) {                    // loads land during compute
            const int n1 = n0 + 64;
            const ushort* hsrc = h + (size_t)((size_t)b * NN + n1) * C_PAD;
            #pragma unroll
            for (int i = 0; i < NKLD; ++i)
                kreg[i] = *(const short8*)&hsrc[(t + i * 256) * 8];
            #pragma unroll
            for (int i = 0; i < NVLD; ++i) {
                const int id = t + i * 256, c = id >> 3, pt = id & 7;
                vreg[i] = *(const short8*)&hT[((size_t)b * C_PAD + c) * NN + n1 + pt * 8];
            }
            if (t < 64) sqreg = sqg[(size_t)b * NN + n1 + t];
        }
        __syncthreads();                       // tile visible

        // ---- S = Q.K^T, 4 col-subtiles of 16 ----
        f32x4 s[4];
        #pragma unroll
        for (int ns = 0; ns < 4; ++ns) {
            f32x4 acc = (f32x4){0.f, 0.f, 0.f, 0.f};
            #pragma unroll
            for (int kf = 0; kf < KF; ++kf) {
                const short8 bf = *(const short8*)&Krow[(ns * 16 + colid) * KST + kf * 32 + quad * 8];
                acc = __builtin_amdgcn_mfma_f32_16x16x32_bf16(qf[kf], bf, acc, 0, 0, 0);
            }
            s[ns] = acc;
        }

        // ---- p = exp2((2*s - sq_m - sq_n) * log2e); no reductions ----
        #pragma unroll
        for (int ns = 0; ns < 4; ++ns) {
            const float bmL = sqs[ns * 16 + colid] * LOG2E;
            #pragma unroll
            for (int r = 0; r < 4; ++r) {
                const float p = exp2f(fmaf(s[ns][r], TWOL2E, -(bmL + sqnL[r])));
                rs[r] += p;
                PO[(quad * 4 + r) * POS + ns * 16 + colid] = f2bf(p);
            }
        }
        // PO is wave-private: same-wave write->read needs only lgkmcnt(0)
        __asm__ volatile("s_waitcnt lgkmcnt(0)" ::: "memory");

        // ---- O += P @ V ----
        #pragma unroll
        for (int kf2 = 0; kf2 < 2; ++kf2) {
            const short8 pa = *(const short8*)&PO[colid * POS + kf2 * 32 + quad * 8];
            #pragma unroll
            for (int cs = 0; cs < CS; ++cs) {
                const short8 vb = *(const short8*)&Vcol[(cs * 16 + colid) * VST + kf2 * 32 + quad * 8];
                o[cs] = __builtin_amdgcn_mfma_f32_16x16x32_bf16(pa, vb, o[cs], 0, 0, 0);
            }
        }
    }
    __syncthreads();                           // Krow free for reuse as Tbuf

    // ---- denominator: reduce per-lane parts across the 16 cols ----
    #pragma unroll
    for (int m = 1; m <= 8; m <<= 1)
        #pragma unroll
        for (int r = 0; r < 4; ++r) rs[r] += __shfl_xor(rs[r], m);
    #pragma unroll
    for (int r = 0; r < 4; ++r) rs[r] = 1.f / rs[r];

    // ---- normalize, round-trip O through LDS, project with MFMA ----
    #pragma unroll
    for (int cs = 0; cs < CS; ++cs)
        #pragma unroll
        for (int r = 0; r < 4; ++r)
            PO[(quad * 4 + r) * POS + cs * 16 + colid] = f2bf(o[cs][r] * rs[r]);
    __asm__ volatile("s_waitcnt lgkmcnt(0)" ::: "memory");

    short8 oa[KF];
    #pragma unroll
    for (int kf = 0; kf < KF; ++kf)
        oa[kf] = *(const short8*)&PO[colid * POS + kf * 32 + quad * 8];

    ushort* Tbuf = Krow;   // reuse (stride 72), Krow dead after main loop
    float rsq[4] = {0.f, 0.f, 0.f, 0.f};
    float msum = 0.f;

    #pragma unroll
    for (int js = 0; js < (HAS_OUT ? 4 : JS); ++js) {
        float v[4];
        if (js < JS) {
            f32x4 acc = (f32x4){0.f, 0.f, 0.f, 0.f};
            #pragma unroll
            for (int kf = 0; kf < KF; ++kf) {
                const short8 wb = *(const short8*)&Wt[(js * 16 + colid) * POS + kf * 32 + quad * 8];
                acc = __builtin_amdgcn_mfma_f32_16x16x32_bf16(oa[kf], wb, acc, 0, 0, 0);
            }
            const float bj = biasS[js * 16 + colid];
            #pragma unroll
            for (int r = 0; r < 4; ++r) v[r] = fmaxf(acc[r] + bj, 0.f);
        } else {
            #pragma unroll
            for (int r = 0; r < 4; ++r) v[r] = 0.f;   // zero-pad cols 48..63
        }
        if (HAS_OUT) {
            #pragma unroll
            for (int r = 0; r < 4; ++r) {
                const int grow = n0blk + w * 16 + quad * 4 + r;
                ho[(size_t)((size_t)b * NN + grow) * 64 + js * 16 + colid] = f2bf(v[r]);
                Tbuf[(js * 16 + colid) * 72 + w * 16 + quad * 4 + r] = f2bf(v[r]);
                rsq[r] += v[r] * v[r];
            }
        }
        if (DO_MEAN) {
            #pragma unroll
            for (int r = 0; r < 4; ++r) msum += v[r];
        }
    }

    if (HAS_OUT) {
        #pragma unroll
        for (int m = 1; m <= 8; m <<= 1)
            #pragma unroll
            for (int r = 0; r < 4; ++r) rsq[r] += __shfl_xor(rsq[r], m);
        if (colid == 0) {
            #pragma unroll
            for (int r = 0; r < 4; ++r)
                sqo[(size_t)b * NN + n0blk + w * 16 + quad * 4 + r] = rsq[r];
        }
        __syncthreads();
        // coalesced transposed store: hoT[b][c][n]
        for (int id = t; id < 64 * 8; id += 256) {
            const int row = id >> 3, part = id & 7;
            *(short8*)&hoT[((size_t)b * 64 + row) * NN + n0blk + part * 8] =
                *(const short8*)&Tbuf[row * 72 + part * 8];
        }
    }
    if (DO_MEAN) {
        msum += __shfl_xor(msum, 16);
        msum += __shfl_xor(msum, 32);
        if (lane < C_OUT) atomicAdd(&mean_out[b * C_OUT + lane], msum * (1.f / NN));
    }
}

// ---------------------------------------------------------------------------
// Final classifier + softmax over 2 logits. 64 threads = 32 batches x 2.
// ---------------------------------------------------------------------------
__global__ __launch_bounds__(64) void final_kernel(
    const float* __restrict__ mean, const float* __restrict__ Wf,
    const float* __restrict__ bf, float* __restrict__ out)
{
    const int t = threadIdx.x;
    const int b = t >> 1, k = t & 1;
    float acc = bf[k];
    #pragma unroll
    for (int c = 0; c < H4; ++c) acc += mean[b * H4 + c] * Wf[c * 2 + k];
    const float other = __shfl_xor(acc, 1);
    const float mx = fmaxf(acc, other);
    const float e  = __expf(acc - mx);
    const float eo = __expf(other - mx);
    out[t] = e / (e + eo);
}

extern "C" void kernel_launch(void* const* d_in, const int* in_sizes, int n_in,
                              void* d_out, int out_size, void* d_ws, size_t ws_size,
                              hipStream_t stream) {
    const float* x   = (const float*)d_in[0];
    const float* W1  = (const float*)d_in[1];
    const float* b1  = (const float*)d_in[2];
    const float* W2  = (const float*)d_in[3];
    const float* b2  = (const float*)d_in[4];
    const float* Wg1 = (const float*)d_in[5];
    const float* bg1 = (const float*)d_in[6];
    const float* Wg2 = (const float*)d_in[7];
    const float* bg2 = (const float*)d_in[8];
    const float* Wf  = (const float*)d_in[9];
    const float* bf  = (const float*)d_in[10];

    ushort* h2  = (ushort*)d_ws;                         // [B*N][96] bf16
    ushort* h2T = h2  + (size_t)BB * NN * 96;            // [B][96][N] bf16
    float*  sq2 = (float*)(h2T + (size_t)BB * 96 * NN);  // [B*N]
    ushort* h3  = (ushort*)(sq2 + (size_t)BB * NN);      // [B*N][64] bf16
    ushort* h3T = h3  + (size_t)BB * NN * 64;            // [B][64][N] bf16
    float*  sq3 = (float*)(h3T + (size_t)BB * 64 * NN);  // [B*N]
    float*  meanb = sq3 + (size_t)BB * NN;               // [B*5]
    ushort* Wt1 = (ushort*)(meanb + BB * H4 + 27);       // [160][320] bf16 (16B-align: 160+27+..)
    // (meanb+BB*H4 = +160 floats = 640B, already 16B aligned; +27 pads to keep
    //  Wt1 16B aligned: 640+108=748 -> NOT aligned. Use explicit alignment:)
    Wt1 = (ushort*)(((uintptr_t)(meanb + BB * H4) + 15) & ~(uintptr_t)15);
    ushort* Wt2 = Wt1 + (size_t)H1 * D_IN;               // [80][160] bf16

    hipMemsetAsync(meanb, 0, BB * H4 * sizeof(float), stream);

    prep_weights_kernel<<<64, 256, 0, stream>>>(W1, W2, Wt1, Wt2);
    mlp_mfma_kernel<<<BB * NN / 64, 256, 0, stream>>>(x, Wt1, b1, Wt2, b2, h2, h2T, sq2);
    attn_conv_kernel<96, 80, 40, 3, true,  false><<<BB * NN / 64, 256, 0, stream>>>(
        h2, h2T, sq2, Wg1, bg1, h3, h3T, sq3, nullptr);
    attn_conv_kernel<64, 40, 5, 1, false, true><<<BB * NN / 64, 256, 0, stream>>>(
        h3, h3T, sq3, Wg2, bg2, nullptr, nullptr, nullptr, meanb);
    final_kernel<<<1, 64, 0, stream>>>(meanb, Wf, bf, (float*)d_out);
}